// Round 4
// baseline (407.517 us; speedup 1.0000x reference)
//
#include <hip/hip_runtime.h>
#include <hip/hip_bf16.h>

typedef unsigned short u16;
typedef __attribute__((ext_vector_type(8))) short bf16x8;
typedef __attribute__((ext_vector_type(4))) float f32x4;

#define SEQ_L 4096
#define HEAD_D 128
#define M_TOT 16384   // B*L

__device__ __forceinline__ float bf2f(u16 x) {
    unsigned u = ((unsigned)x) << 16;
    return __builtin_bit_cast(float, u);
}
__device__ __forceinline__ u16 f2bf(float f) {
    unsigned u = __builtin_bit_cast(unsigned, f);
    u += 0x7FFFu + ((u >> 16) & 1u);   // round-to-nearest-even
    return (u16)(u >> 16);
}

// fp32 vs bf16 storage fingerprint: bf16 N(0,1)/xavier data has every u16
// well-formed (exp in [96,143]) or zero; fp32 low-halves are uniform noise.
__device__ bool buf_is_fp32(const void* p) {
    const u16* h = (const u16*)p;
    int c = 0;
    #pragma unroll 4
    for (int i = 0; i < 64; i++) {
        u16 x = h[2 * i];
        int e = (x >> 7) & 0xFF;
        if (x == 0 || (e >= 96 && e <= 143)) c++;
    }
    return c < 60;
}

// ---- canonicalize the six [B,L,128] inputs into x[16384,768] bf16 ----
__global__ __launch_bounds__(256) void pack_x(
    const void* __restrict__ in0, const void* __restrict__ in1, const void* __restrict__ in2,
    const void* __restrict__ in3, const void* __restrict__ in4, const void* __restrict__ in5,
    u16* __restrict__ x) {
    const void* ins[6] = {in0, in1, in2, in3, in4, in5};
    int which = blockIdx.y;
    const void* src = ins[which];
    __shared__ bool f32;
    if (threadIdx.x == 0) f32 = buf_is_fp32(src);
    __syncthreads();
    int j = blockIdx.x * 256 + threadIdx.x;          // 0 .. 2097151
    int m = j >> 7, d = j & 127;
    u16 v = f32 ? f2bf(((const float*)src)[j]) : ((const u16*)src)[j];
    x[(size_t)m * 768 + which * 128 + d] = v;
}

// ---- canonicalize a flat buffer to bf16 ----
__global__ __launch_bounds__(256) void conv_bf16(const void* __restrict__ src,
                                                 u16* __restrict__ dst, int n) {
    __shared__ bool f32;
    if (threadIdx.x == 0) f32 = buf_is_fp32(src);
    __syncthreads();
    int i = blockIdx.x * 256 + threadIdx.x;
    if (i >= n) return;
    dst[i] = f32 ? f2bf(((const float*)src)[i]) : ((const u16*)src)[i];
}

// ---- canonicalize a flat buffer to fp32 (biases) ----
__global__ __launch_bounds__(256) void conv_f32(const void* __restrict__ src,
                                                float* __restrict__ dst, int n) {
    __shared__ bool f32;
    if (threadIdx.x == 0) f32 = buf_is_fp32(src);
    __syncthreads();
    int i = blockIdx.x * 256 + threadIdx.x;
    if (i >= n) return;
    dst[i] = f32 ? ((const float*)src)[i] : bf2f(((const u16*)src)[i]);
}

// ---------------- mask compaction: [4096,4096] -> [64,64] uint8 ----------------
// Elements [0][0],[0][1] are guaranteed true (diagonal block); first 32-bit word
// fingerprints storage: 0x01010101/0xFFFFFFFF u8 | 0x3F803F80 bf16 | 0x3C003C00
// f16 | else 4-byte (int32/fp32).
__global__ void mask_compact(const void* __restrict__ mask, unsigned char* __restrict__ cmask) {
    int i = blockIdx.x * blockDim.x + threadIdx.x;   // 0..4095
    if (i >= 4096) return;
    int bi = i >> 6, bj = i & 63;
    size_t e = (size_t)(bi * 64) * SEQ_L + (size_t)bj * 64;
    const unsigned char* p8 = (const unsigned char*)mask;
    unsigned w0 = *(const unsigned*)mask;
    bool v;
    if (w0 == 0x01010101u || w0 == 0xFFFFFFFFu)      v = p8[e] != 0;
    else if (w0 == 0x3F803F80u || w0 == 0x3C003C00u) v = ((const u16*)mask)[e] != 0;
    else                                             v = ((const unsigned*)mask)[e] != 0;
    cmask[i] = v ? 1 : 0;
}

// ---------------- QKV GEMM: qkv[m,o] = sum_k x[m,k]*W[o,k] + b[o], fp32 out ----------------
__global__ __launch_bounds__(256) void qkv_gemm(
    const u16* __restrict__ X, const u16* __restrict__ W, const float* __restrict__ bias,
    float* __restrict__ out) {
    __shared__ __align__(16) u16 As[64 * 72];
    __shared__ __align__(16) u16 Bs[64 * 72];
    int m0 = blockIdx.x * 64, n0 = blockIdx.y * 64;
    int tid = threadIdx.x, lane = tid & 63, w = tid >> 6;
    int ln = lane & 15, quad = lane >> 4;
    f32x4 acc[4] = {};
    for (int kk = 0; kk < 768; kk += 64) {
        __syncthreads();
        #pragma unroll
        for (int ch = tid; ch < 512; ch += 256) {
            int row = ch >> 3, c8 = ch & 7;
            *(uint4*)(As + row * 72 + c8 * 8) =
                *(const uint4*)(X + (size_t)(m0 + row) * 768 + kk + c8 * 8);
            *(uint4*)(Bs + row * 72 + c8 * 8) =
                *(const uint4*)(W + (size_t)(n0 + row) * 768 + kk + c8 * 8);
        }
        __syncthreads();
        #pragma unroll
        for (int s = 0; s < 2; s++) {
            bf16x8 af = *(const bf16x8*)(As + (w * 16 + ln) * 72 + 32 * s + 8 * quad);
            #pragma unroll
            for (int t = 0; t < 4; t++) {
                bf16x8 bfr = *(const bf16x8*)(Bs + (t * 16 + ln) * 72 + 32 * s + 8 * quad);
                acc[t] = __builtin_amdgcn_mfma_f32_16x16x32_bf16(af, bfr, acc[t], 0, 0, 0);
            }
        }
    }
    #pragma unroll
    for (int t = 0; t < 4; t++) {
        int col = n0 + t * 16 + ln;
        float bv = bias[col];
        #pragma unroll
        for (int r = 0; r < 4; r++) {
            int row = m0 + w * 16 + 4 * quad + r;
            out[(size_t)row * 768 + col] = acc[t][r] + bv;
        }
    }
}

// ---------------- block-sparse flash attention (fp32 qkv in, fp32 attn out) ----------------
__global__ __launch_bounds__(256) void attn_kernel(
    const float* __restrict__ qkv, const unsigned char* __restrict__ cmask,
    float* __restrict__ attn_out) {
    __shared__ __align__(16) u16 Ks[64 * 136];      // K rows [64][128], stride 136
    __shared__ __align__(16) u16 Vt[128 * 72];      // V transposed [d][k], stride 72
    __shared__ __align__(16) u16 Ps[4][16 * 72];    // per-wave P staging

    int idx = blockIdx.x;
    int qi = idx & 63, c = (idx >> 6) & 1, b = idx >> 7;
    int tid = threadIdx.x, lane = tid & 63, w = tid >> 6;
    int ln = lane & 15, quad = lane >> 4;
    const float scale = 0.08838834764831845f;  // 1/sqrt(128)

    // Q fragments: A[m=ln][k=32s+8*quad+j]
    bf16x8 qf[4];
    {
        size_t grow = (size_t)(b * SEQ_L + qi * 64 + w * 16 + ln);
        const float* qp = qkv + grow * 768 + c * 128;
        #pragma unroll
        for (int s = 0; s < 4; s++) {
            float4 a = *(const float4*)(qp + 32 * s + 8 * quad);
            float4 bq = *(const float4*)(qp + 32 * s + 8 * quad + 4);
            bf16x8 t;
            t[0] = (short)f2bf(a.x); t[1] = (short)f2bf(a.y);
            t[2] = (short)f2bf(a.z); t[3] = (short)f2bf(a.w);
            t[4] = (short)f2bf(bq.x); t[5] = (short)f2bf(bq.y);
            t[6] = (short)f2bf(bq.z); t[7] = (short)f2bf(bq.w);
            qf[s] = t;
        }
    }
    float m_st[4], l_st[4];
    #pragma unroll
    for (int r = 0; r < 4; r++) { m_st[r] = -1e30f; l_st[r] = 0.f; }
    f32x4 accO[8] = {};

    const unsigned char* mrow = cmask + qi * 64;
    for (int kb = 0; kb <= qi; kb++) {
        if (!mrow[kb]) continue;   // block-uniform
        __syncthreads();
        const float* kbase = qkv + (size_t)(b * SEQ_L + kb * 64) * 768 + 256 + c * 128;
        const float* vbase = qkv + (size_t)(b * SEQ_L + kb * 64) * 768 + 512 + c * 128;
        #pragma unroll
        for (int ch = tid; ch < 2048; ch += 256) {
            int row = ch >> 5, c4 = ch & 31;     // 64 rows x 32 float4-chunks
            float4 kv = *(const float4*)(kbase + (size_t)row * 768 + c4 * 4);
            Ks[row * 136 + c4 * 4 + 0] = f2bf(kv.x);
            Ks[row * 136 + c4 * 4 + 1] = f2bf(kv.y);
            Ks[row * 136 + c4 * 4 + 2] = f2bf(kv.z);
            Ks[row * 136 + c4 * 4 + 3] = f2bf(kv.w);
            float4 vv = *(const float4*)(vbase + (size_t)row * 768 + c4 * 4);
            Vt[(c4 * 4 + 0) * 72 + row] = f2bf(vv.x);
            Vt[(c4 * 4 + 1) * 72 + row] = f2bf(vv.y);
            Vt[(c4 * 4 + 2) * 72 + row] = f2bf(vv.z);
            Vt[(c4 * 4 + 3) * 72 + row] = f2bf(vv.w);
        }
        __syncthreads();

        // S = Q K^T : D[m=4*quad+r][n=ln+16t]
        f32x4 accS[4] = {};
        #pragma unroll
        for (int s = 0; s < 4; s++) {
            #pragma unroll
            for (int t = 0; t < 4; t++) {
                bf16x8 bfr = *(const bf16x8*)(Ks + (t * 16 + ln) * 136 + 32 * s + 8 * quad);
                accS[t] = __builtin_amdgcn_mfma_f32_16x16x32_bf16(qf[s], bfr, accS[t], 0, 0, 0);
            }
        }

        // online softmax per row m = 4*quad + r
        float P[4][4];
        #pragma unroll
        for (int r = 0; r < 4; r++) {
            float sv[4];
            float mx = -1e30f;
            #pragma unroll
            for (int t = 0; t < 4; t++) { sv[t] = accS[t][r] * scale; mx = fmaxf(mx, sv[t]); }
            #pragma unroll
            for (int off = 1; off < 16; off <<= 1) mx = fmaxf(mx, __shfl_xor(mx, off, 64));
            float nm = fmaxf(m_st[r], mx);
            float alpha = __expf(m_st[r] - nm);
            m_st[r] = nm;
            float rs = 0.f;
            #pragma unroll
            for (int t = 0; t < 4; t++) { float p = __expf(sv[t] - nm); P[t][r] = p; rs += p; }
            #pragma unroll
            for (int off = 1; off < 16; off <<= 1) rs += __shfl_xor(rs, off, 64);
            l_st[r] = l_st[r] * alpha + rs;
            #pragma unroll
            for (int nt = 0; nt < 8; nt++) accO[nt][r] *= alpha;
        }
        // stage P: C/D layout -> A-operand layout via LDS
        #pragma unroll
        for (int t = 0; t < 4; t++)
            #pragma unroll
            for (int r = 0; r < 4; r++)
                Ps[w][(4 * quad + r) * 72 + ln + 16 * t] = f2bf(P[t][r]);
        __syncthreads();

        // O += P V
        #pragma unroll
        for (int s2 = 0; s2 < 2; s2++) {
            bf16x8 pf = *(const bf16x8*)(&Ps[w][ln * 72 + 32 * s2 + 8 * quad]);
            #pragma unroll
            for (int nt = 0; nt < 8; nt++) {
                bf16x8 vf = *(const bf16x8*)(Vt + (nt * 16 + ln) * 72 + 32 * s2 + 8 * quad);
                accO[nt] = __builtin_amdgcn_mfma_f32_16x16x32_bf16(pf, vf, accO[nt], 0, 0, 0);
            }
        }
    }

    #pragma unroll
    for (int nt = 0; nt < 8; nt++) {
        int col = c * 128 + nt * 16 + ln;
        #pragma unroll
        for (int r = 0; r < 4; r++) {
            int row = b * SEQ_L + qi * 64 + w * 16 + 4 * quad + r;
            float inv = 1.0f / fmaxf(l_st[r], 1e-20f);
            attn_out[(size_t)row * 256 + col] = accO[nt][r] * inv;
        }
    }
}

// ---------------- out projection: attn[16384,256] @ Wout^T + b -> fp32 split halves ----------------
__global__ __launch_bounds__(256) void out_gemm(
    const float* __restrict__ A, const u16* __restrict__ W, const float* __restrict__ bias,
    float* __restrict__ out) {
    __shared__ __align__(16) u16 As[64 * 72];
    __shared__ __align__(16) u16 Bs[64 * 72];
    int m0 = blockIdx.x * 64, n0 = blockIdx.y * 64;
    int tid = threadIdx.x, lane = tid & 63, w = tid >> 6;
    int ln = lane & 15, quad = lane >> 4;
    f32x4 acc[4] = {};
    for (int kk = 0; kk < 256; kk += 64) {
        __syncthreads();
        #pragma unroll
        for (int ch = tid; ch < 512; ch += 256) {
            int row = ch >> 3, c8 = ch & 7;
            if (ch < 512) {
                // A: fp32 -> bf16 into LDS (two float4 per 8-elem chunk)
                const float* ap = A + (size_t)(m0 + row) * 256 + kk + c8 * 8;
                float4 a0 = *(const float4*)(ap);
                float4 a1 = *(const float4*)(ap + 4);
                u16* dst = As + row * 72 + c8 * 8;
                dst[0] = f2bf(a0.x); dst[1] = f2bf(a0.y); dst[2] = f2bf(a0.z); dst[3] = f2bf(a0.w);
                dst[4] = f2bf(a1.x); dst[5] = f2bf(a1.y); dst[6] = f2bf(a1.z); dst[7] = f2bf(a1.w);
                *(uint4*)(Bs + row * 72 + c8 * 8) =
                    *(const uint4*)(W + (size_t)(n0 + row) * 256 + kk + c8 * 8);
            }
        }
        __syncthreads();
        #pragma unroll
        for (int s = 0; s < 2; s++) {
            bf16x8 af = *(const bf16x8*)(As + (w * 16 + ln) * 72 + 32 * s + 8 * quad);
            #pragma unroll
            for (int t = 0; t < 4; t++) {
                bf16x8 bfr = *(const bf16x8*)(Bs + (t * 16 + ln) * 72 + 32 * s + 8 * quad);
                acc[t] = __builtin_amdgcn_mfma_f32_16x16x32_bf16(af, bfr, acc[t], 0, 0, 0);
            }
        }
    }
    const size_t half = (size_t)M_TOT * 128;
    #pragma unroll
    for (int t = 0; t < 4; t++) {
        int col = n0 + t * 16 + ln;
        float bv = bias[col];
        float* base = (col < 128) ? (out + col) : (out + half + (col - 128));
        #pragma unroll
        for (int r = 0; r < 4; r++) {
            int row = m0 + w * 16 + 4 * quad + r;
            base[(size_t)row * 128] = acc[t][r] + bv;
        }
    }
}

extern "C" void kernel_launch(void* const* d_in, const int* in_sizes, int n_in,
                              void* d_out, int out_size, void* d_ws, size_t ws_size,
                              hipStream_t stream) {
    const void* mask = d_in[10];
    char* ws = (char*)d_ws;
    // fp32 first (keeps 16B alignment), then bf16 regions, then cmask. ~89.3 MiB total.
    float* qkv_f32  = (float*)ws;                                  // 16384*768*4 = 50.3 MB
    float* attn_f32 = qkv_f32 + (size_t)M_TOT * 768;               // 16.8 MB
    float* bqkv_f   = attn_f32 + (size_t)M_TOT * 256;              // 3 KB
    float* bout_f   = bqkv_f + 768;                                // 1 KB
    u16*   x_bf     = (u16*)(bout_f + 256);                        // 25.2 MB
    u16*   Wqkv_bf  = x_bf + (size_t)M_TOT * 768;                  // 1.18 MB
    u16*   Wout_bf  = Wqkv_bf + 589824;                            // 0.13 MB
    unsigned char* cmask = (unsigned char*)(Wout_bf + 65536);      // 4 KB

    hipLaunchKernelGGL(pack_x, dim3(8192, 6), dim3(256), 0, stream,
                       d_in[0], d_in[1], d_in[2], d_in[3], d_in[4], d_in[5], x_bf);
    hipLaunchKernelGGL(conv_bf16, dim3(2304), dim3(256), 0, stream, d_in[6], Wqkv_bf, 589824);
    hipLaunchKernelGGL(conv_f32, dim3(3), dim3(256), 0, stream, d_in[7], bqkv_f, 768);
    hipLaunchKernelGGL(conv_bf16, dim3(256), dim3(256), 0, stream, d_in[8], Wout_bf, 65536);
    hipLaunchKernelGGL(conv_f32, dim3(1), dim3(256), 0, stream, d_in[9], bout_f, 256);
    hipLaunchKernelGGL(mask_compact, dim3(16), dim3(256), 0, stream, mask, cmask);

    hipLaunchKernelGGL(qkv_gemm, dim3(256, 12), dim3(256), 0, stream,
                       x_bf, Wqkv_bf, bqkv_f, qkv_f32);
    hipLaunchKernelGGL(attn_kernel, dim3(512), dim3(256), 0, stream, qkv_f32, cmask, attn_f32);
    hipLaunchKernelGGL(out_gemm, dim3(256, 4), dim3(256), 0, stream,
                       attn_f32, Wout_bf, bout_f, (float*)d_out);
}

// Round 5
// 259.374 us; speedup vs baseline: 1.5712x; 1.5712x over previous
//
#include <hip/hip_runtime.h>
#include <hip/hip_bf16.h>

typedef unsigned short u16;
typedef __attribute__((ext_vector_type(8))) short bf16x8;
typedef __attribute__((ext_vector_type(4))) float f32x4;

#define SEQ_L 4096
#define M_TOT 16384   // B*L

__device__ __forceinline__ float bf2f(u16 x) {
    unsigned u = ((unsigned)x) << 16;
    return __builtin_bit_cast(float, u);
}
__device__ __forceinline__ u16 f2bf(float f) {
    unsigned u = __builtin_bit_cast(unsigned, f);
    u += 0x7FFFu + ((u >> 16) & 1u);   // round-to-nearest-even
    return (u16)(u >> 16);
}

// ---- pack six fp32 [B,L,128] inputs into x[16384,768] bf16, 8 elems/thread ----
__global__ __launch_bounds__(256) void pack_x(
    const float* __restrict__ in0, const float* __restrict__ in1, const float* __restrict__ in2,
    const float* __restrict__ in3, const float* __restrict__ in4, const float* __restrict__ in5,
    u16* __restrict__ x) {
    const float* ins[6] = {in0, in1, in2, in3, in4, in5};
    int which = blockIdx.y;
    const float* src = ins[which];
    int g = blockIdx.x * 256 + threadIdx.x;        // 0..262143 (16 chunks x 16384 rows)
    int m = g >> 4, c8 = g & 15;
    const float* sp = src + (size_t)m * 128 + c8 * 8;
    float4 a = *(const float4*)sp;
    float4 b = *(const float4*)(sp + 4);
    u16 t[8] = {f2bf(a.x), f2bf(a.y), f2bf(a.z), f2bf(a.w),
                f2bf(b.x), f2bf(b.y), f2bf(b.z), f2bf(b.w)};
    *(uint4*)(x + (size_t)m * 768 + which * 128 + c8 * 8) = *(uint4*)t;
}

// ---- fp32 weight -> bf16, 8 elems/thread ----
__global__ __launch_bounds__(256) void conv_w(const float* __restrict__ src,
                                              u16* __restrict__ dst, int n8) {
    int i = blockIdx.x * 256 + threadIdx.x;
    if (i >= n8) return;
    const float* sp = src + (size_t)i * 8;
    float4 a = *(const float4*)sp;
    float4 b = *(const float4*)(sp + 4);
    u16 t[8] = {f2bf(a.x), f2bf(a.y), f2bf(a.z), f2bf(a.w),
                f2bf(b.x), f2bf(b.y), f2bf(b.z), f2bf(b.w)};
    *(uint4*)(dst + (size_t)i * 8) = *(uint4*)t;
}

// ---------------- mask compaction: [4096,4096] -> [64,64] uint8 ----------------
// First 32-bit word fingerprints storage (elements [0][0],[0][1] are always true).
__global__ void mask_compact(const void* __restrict__ mask, unsigned char* __restrict__ cmask) {
    int i = blockIdx.x * blockDim.x + threadIdx.x;   // 0..4095
    if (i >= 4096) return;
    int bi = i >> 6, bj = i & 63;
    size_t e = (size_t)(bi * 64) * SEQ_L + (size_t)bj * 64;
    const unsigned char* p8 = (const unsigned char*)mask;
    unsigned w0 = *(const unsigned*)mask;
    bool v;
    if (w0 == 0x01010101u || w0 == 0xFFFFFFFFu)      v = p8[e] != 0;
    else if (w0 == 0x3F803F80u || w0 == 0x3C003C00u) v = ((const u16*)mask)[e] != 0;
    else                                             v = ((const unsigned*)mask)[e] != 0;
    cmask[i] = v ? 1 : 0;
}

// ---------------- QKV GEMM, 128x128 tile ----------------
// out split: qk[m][0..511] (Q at c*128, K at 256+c*128), V transposed into
// vt[(b*2+c)*128 + d][seq]  (seq-major for attn's V^T staging).
__global__ __launch_bounds__(256) void qkv_gemm(
    const u16* __restrict__ X, const u16* __restrict__ W, const float* __restrict__ bias,
    u16* __restrict__ qk, u16* __restrict__ vt) {
    __shared__ __align__(16) u16 As[128 * 72];
    __shared__ __align__(16) u16 Bs[128 * 72];
    int m0 = blockIdx.x * 128, n0 = blockIdx.y * 128;
    int tid = threadIdx.x, lane = tid & 63, w = tid >> 6;
    int ln = lane & 15, quad = lane >> 4;
    int rw = (w >> 1) * 64, cw = (w & 1) * 64;
    f32x4 acc[4][4] = {};
    for (int kk = 0; kk < 768; kk += 64) {
        __syncthreads();
        #pragma unroll
        for (int ch = tid; ch < 1024; ch += 256) {
            int row = ch >> 3, c8 = ch & 7;
            *(uint4*)(As + row * 72 + c8 * 8) =
                *(const uint4*)(X + (size_t)(m0 + row) * 768 + kk + c8 * 8);
            *(uint4*)(Bs + row * 72 + c8 * 8) =
                *(const uint4*)(W + (size_t)(n0 + row) * 768 + kk + c8 * 8);
        }
        __syncthreads();
        #pragma unroll
        for (int s = 0; s < 2; s++) {
            bf16x8 af[4], bfr[4];
            #pragma unroll
            for (int i = 0; i < 4; i++)
                af[i] = *(const bf16x8*)(As + (rw + i * 16 + ln) * 72 + 32 * s + 8 * quad);
            #pragma unroll
            for (int t = 0; t < 4; t++)
                bfr[t] = *(const bf16x8*)(Bs + (cw + t * 16 + ln) * 72 + 32 * s + 8 * quad);
            #pragma unroll
            for (int i = 0; i < 4; i++)
                #pragma unroll
                for (int t = 0; t < 4; t++)
                    acc[i][t] = __builtin_amdgcn_mfma_f32_16x16x32_bf16(af[i], bfr[t], acc[i][t], 0, 0, 0);
        }
    }
    #pragma unroll
    for (int i = 0; i < 4; i++) {
        int row0 = m0 + rw + i * 16 + 4 * quad;   // 4 consecutive rows
        #pragma unroll
        for (int t = 0; t < 4; t++) {
            int col = n0 + cw + t * 16 + ln;
            float bv = bias[col];
            if (col < 512) {
                #pragma unroll
                for (int r = 0; r < 4; r++)
                    qk[(size_t)(row0 + r) * 512 + col] = f2bf(acc[i][t][r] + bv);
            } else {
                int d = col - 512;                 // c = d>>7, dd = d&127
                int b = row0 >> 12, seq = row0 & 4095;
                u16 pk[4] = {f2bf(acc[i][t][0] + bv), f2bf(acc[i][t][1] + bv),
                             f2bf(acc[i][t][2] + bv), f2bf(acc[i][t][3] + bv)};
                *(ushort4*)(vt + ((size_t)(b * 2 + (d >> 7)) * 128 + (d & 127)) * SEQ_L + seq)
                    = *(ushort4*)pk;
            }
        }
    }
}

// ---------------- block-sparse flash attention (bf16 in/out) ----------------
__global__ __launch_bounds__(256) void attn_kernel(
    const u16* __restrict__ qk, const u16* __restrict__ vt,
    const unsigned char* __restrict__ cmask, u16* __restrict__ attn_out) {
    __shared__ __align__(16) u16 Ks[64 * 136];      // K rows [64][128], stride 136
    __shared__ __align__(16) u16 Vt[128 * 72];      // V^T [d][k], stride 72
    __shared__ __align__(16) u16 Ps[4][16 * 72];    // per-wave P staging

    int idx = blockIdx.x;
    int qi = 63 - (idx >> 3);          // heavy q-blocks dispatched first
    int sub = idx & 7, c = sub & 1, b = sub >> 1;
    int tid = threadIdx.x, lane = tid & 63, w = tid >> 6;
    int ln = lane & 15, quad = lane >> 4;
    const float scale = 0.08838834764831845f;  // 1/sqrt(128)

    // Q fragments: A[m=ln][k=32s+8*quad+j]
    bf16x8 qf[4];
    {
        size_t grow = (size_t)(b * SEQ_L + qi * 64 + w * 16 + ln);
        const u16* qp = qk + grow * 512 + c * 128;
        #pragma unroll
        for (int s = 0; s < 4; s++) qf[s] = *(const bf16x8*)(qp + 32 * s + 8 * quad);
    }
    float m_st[4], l_st[4];
    #pragma unroll
    for (int r = 0; r < 4; r++) { m_st[r] = -1e30f; l_st[r] = 0.f; }
    f32x4 accO[8] = {};

    const unsigned char* mrow = cmask + qi * 64;
    const u16* vtb0 = vt + (size_t)(b * 2 + c) * 128 * SEQ_L;
    for (int kb = 0; kb <= qi; kb++) {
        if (!mrow[kb]) continue;   // block-uniform branch
        __syncthreads();
        const u16* kbase = qk + (size_t)(b * SEQ_L + kb * 64) * 512 + 256 + c * 128;
        const u16* vtb = vtb0 + kb * 64;
        #pragma unroll
        for (int ch = tid; ch < 1024; ch += 256) {   // K tile: 64 rows x 16 chunks
            int row = ch >> 4, c8 = ch & 15;
            *(uint4*)(Ks + row * 136 + c8 * 8) =
                *(const uint4*)(kbase + (size_t)row * 512 + c8 * 8);
        }
        #pragma unroll
        for (int ch = tid; ch < 1024; ch += 256) {   // V^T tile: 128 d-rows x 8 chunks
            int d = ch >> 3, c8 = ch & 7;
            *(uint4*)(Vt + d * 72 + c8 * 8) =
                *(const uint4*)(vtb + (size_t)d * SEQ_L + c8 * 8);
        }
        __syncthreads();

        // S = Q K^T : D[m=4*quad+r][n=ln+16t]
        f32x4 accS[4] = {};
        #pragma unroll
        for (int s = 0; s < 4; s++) {
            #pragma unroll
            for (int t = 0; t < 4; t++) {
                bf16x8 bfr = *(const bf16x8*)(Ks + (t * 16 + ln) * 136 + 32 * s + 8 * quad);
                accS[t] = __builtin_amdgcn_mfma_f32_16x16x32_bf16(qf[s], bfr, accS[t], 0, 0, 0);
            }
        }

        // online softmax per row m = 4*quad + r
        float P[4][4];
        #pragma unroll
        for (int r = 0; r < 4; r++) {
            float sv[4];
            float mx = -1e30f;
            #pragma unroll
            for (int t = 0; t < 4; t++) { sv[t] = accS[t][r] * scale; mx = fmaxf(mx, sv[t]); }
            #pragma unroll
            for (int off = 1; off < 16; off <<= 1) mx = fmaxf(mx, __shfl_xor(mx, off, 64));
            float nm = fmaxf(m_st[r], mx);
            float alpha = __expf(m_st[r] - nm);
            m_st[r] = nm;
            float rs = 0.f;
            #pragma unroll
            for (int t = 0; t < 4; t++) { float p = __expf(sv[t] - nm); P[t][r] = p; rs += p; }
            #pragma unroll
            for (int off = 1; off < 16; off <<= 1) rs += __shfl_xor(rs, off, 64);
            l_st[r] = l_st[r] * alpha + rs;
            #pragma unroll
            for (int nt = 0; nt < 8; nt++) accO[nt][r] *= alpha;
        }
        // stage P: C/D layout -> A-operand layout via LDS
        #pragma unroll
        for (int t = 0; t < 4; t++)
            #pragma unroll
            for (int r = 0; r < 4; r++)
                Ps[w][(4 * quad + r) * 72 + ln + 16 * t] = f2bf(P[t][r]);
        __syncthreads();

        // O += P V
        #pragma unroll
        for (int s2 = 0; s2 < 2; s2++) {
            bf16x8 pf = *(const bf16x8*)(&Ps[w][ln * 72 + 32 * s2 + 8 * quad]);
            #pragma unroll
            for (int nt = 0; nt < 8; nt++) {
                bf16x8 vf = *(const bf16x8*)(Vt + (nt * 16 + ln) * 72 + 32 * s2 + 8 * quad);
                accO[nt] = __builtin_amdgcn_mfma_f32_16x16x32_bf16(pf, vf, accO[nt], 0, 0, 0);
            }
        }
    }

    #pragma unroll
    for (int nt = 0; nt < 8; nt++) {
        int col = c * 128 + nt * 16 + ln;
        #pragma unroll
        for (int r = 0; r < 4; r++) {
            int row = b * SEQ_L + qi * 64 + w * 16 + 4 * quad + r;
            float inv = 1.0f / fmaxf(l_st[r], 1e-20f);
            attn_out[(size_t)row * 256 + col] = f2bf(accO[nt][r] * inv);
        }
    }
}

// ---------------- out projection: attn[16384,256](bf16) @ Wout^T + b -> fp32 halves ----------------
__global__ __launch_bounds__(256) void out_gemm(
    const u16* __restrict__ A, const u16* __restrict__ W, const float* __restrict__ bias,
    float* __restrict__ out) {
    __shared__ __align__(16) u16 As[64 * 72];
    __shared__ __align__(16) u16 Bs[64 * 72];
    int m0 = blockIdx.x * 64, n0 = blockIdx.y * 64;
    int tid = threadIdx.x, lane = tid & 63, w = tid >> 6;
    int ln = lane & 15, quad = lane >> 4;
    f32x4 acc[4] = {};
    for (int kk = 0; kk < 256; kk += 64) {
        __syncthreads();
        #pragma unroll
        for (int ch = tid; ch < 512; ch += 256) {
            int row = ch >> 3, c8 = ch & 7;
            *(uint4*)(As + row * 72 + c8 * 8) =
                *(const uint4*)(A + (size_t)(m0 + row) * 256 + kk + c8 * 8);
            *(uint4*)(Bs + row * 72 + c8 * 8) =
                *(const uint4*)(W + (size_t)(n0 + row) * 256 + kk + c8 * 8);
        }
        __syncthreads();
        #pragma unroll
        for (int s = 0; s < 2; s++) {
            bf16x8 af = *(const bf16x8*)(As + (w * 16 + ln) * 72 + 32 * s + 8 * quad);
            #pragma unroll
            for (int t = 0; t < 4; t++) {
                bf16x8 bfr = *(const bf16x8*)(Bs + (t * 16 + ln) * 72 + 32 * s + 8 * quad);
                acc[t] = __builtin_amdgcn_mfma_f32_16x16x32_bf16(af, bfr, acc[t], 0, 0, 0);
            }
        }
    }
    const size_t half = (size_t)M_TOT * 128;
    #pragma unroll
    for (int t = 0; t < 4; t++) {
        int col = n0 + t * 16 + ln;
        float bv = bias[col];
        float* base = (col < 128) ? (out + col) : (out + half + (col - 128));
        #pragma unroll
        for (int r = 0; r < 4; r++) {
            int row = m0 + w * 16 + 4 * quad + r;
            base[(size_t)row * 128] = acc[t][r] + bv;
        }
    }
}

extern "C" void kernel_launch(void* const* d_in, const int* in_sizes, int n_in,
                              void* d_out, int out_size, void* d_ws, size_t ws_size,
                              hipStream_t stream) {
    char* ws = (char*)d_ws;
    u16* x_bf    = (u16*)ws;                          // 16384*768  = 25.2 MB
    u16* qk_buf  = x_bf + (size_t)M_TOT * 768;        // 16384*512  = 16.8 MB
    u16* vt_buf  = qk_buf + (size_t)M_TOT * 512;      // 1024*4096  =  8.4 MB
    u16* attn_bf = vt_buf + (size_t)1024 * SEQ_L;     // 16384*256  =  8.4 MB
    u16* Wqkv_bf = attn_bf + (size_t)M_TOT * 256;     // 589824     =  1.2 MB
    u16* Wout_bf = Wqkv_bf + 589824;                  // 65536
    unsigned char* cmask = (unsigned char*)(Wout_bf + 65536);

    hipLaunchKernelGGL(pack_x, dim3(1024, 6), dim3(256), 0, stream,
                       (const float*)d_in[0], (const float*)d_in[1], (const float*)d_in[2],
                       (const float*)d_in[3], (const float*)d_in[4], (const float*)d_in[5], x_bf);
    hipLaunchKernelGGL(conv_w, dim3(288), dim3(256), 0, stream,
                       (const float*)d_in[6], Wqkv_bf, 73728);
    hipLaunchKernelGGL(conv_w, dim3(32), dim3(256), 0, stream,
                       (const float*)d_in[8], Wout_bf, 8192);
    hipLaunchKernelGGL(mask_compact, dim3(16), dim3(256), 0, stream, d_in[10], cmask);

    hipLaunchKernelGGL(qkv_gemm, dim3(128, 6), dim3(256), 0, stream,
                       x_bf, Wqkv_bf, (const float*)d_in[7], qk_buf, vt_buf);
    hipLaunchKernelGGL(attn_kernel, dim3(512), dim3(256), 0, stream,
                       qk_buf, vt_buf, cmask, attn_bf);
    hipLaunchKernelGGL(out_gemm, dim3(256, 4), dim3(256), 0, stream,
                       attn_bf, Wout_bf, (const float*)d_in[9], (float*)d_out);
}

// Round 6
// 223.971 us; speedup vs baseline: 1.8195x; 1.1581x over previous
//
#include <hip/hip_runtime.h>
#include <hip/hip_bf16.h>

typedef unsigned short u16;
typedef __attribute__((ext_vector_type(8))) short bf16x8;
typedef __attribute__((ext_vector_type(4))) float f32x4;

#define SEQ_L 4096
#define M_TOT 16384   // B*L

__device__ __forceinline__ float bf2f(u16 x) {
    unsigned u = ((unsigned)x) << 16;
    return __builtin_bit_cast(float, u);
}
__device__ __forceinline__ u16 f2bf(float f) {
    unsigned u = __builtin_bit_cast(unsigned, f);
    u += 0x7FFFu + ((u >> 16) & 1u);   // round-to-nearest-even
    return (u16)(u >> 16);
}
// async 16B global->LDS (direct-to-LDS DMA; LDS dest = uniform base + lane*16)
__device__ __forceinline__ void gload16(const u16* g, u16* l) {
    __builtin_amdgcn_global_load_lds(
        (const __attribute__((address_space(1))) unsigned int*)g,
        (__attribute__((address_space(3))) unsigned int*)l, 16, 0, 0);
}

// ---- pack six fp32 [B,L,128] inputs into x[16384,768] bf16, 8 elems/thread ----
__global__ __launch_bounds__(256) void pack_x(
    const float* __restrict__ in0, const float* __restrict__ in1, const float* __restrict__ in2,
    const float* __restrict__ in3, const float* __restrict__ in4, const float* __restrict__ in5,
    u16* __restrict__ x) {
    const float* ins[6] = {in0, in1, in2, in3, in4, in5};
    int which = blockIdx.y;
    const float* src = ins[which];
    int g = blockIdx.x * 256 + threadIdx.x;        // 0..262143
    int m = g >> 4, c8 = g & 15;
    const float* sp = src + (size_t)m * 128 + c8 * 8;
    float4 a = *(const float4*)sp;
    float4 b = *(const float4*)(sp + 4);
    u16 t[8] = {f2bf(a.x), f2bf(a.y), f2bf(a.z), f2bf(a.w),
                f2bf(b.x), f2bf(b.y), f2bf(b.z), f2bf(b.w)};
    *(uint4*)(x + (size_t)m * 768 + which * 128 + c8 * 8) = *(uint4*)t;
}

// ---- merged: Wqkv->bf16 (73728 chunks) | Wout->bf16 (8192 chunks) | mask compact (4096) ----
__global__ __launch_bounds__(256) void prep(
    const float* __restrict__ Wqkv, const float* __restrict__ Wout, const void* __restrict__ mask,
    u16* __restrict__ Wqkv_bf, u16* __restrict__ Wout_bf, unsigned char* __restrict__ cmask) {
    int id = blockIdx.x * 256 + threadIdx.x;
    if (id < 73728 + 8192) {
        const float* src = (id < 73728) ? Wqkv : Wout;
        u16* dst = (id < 73728) ? Wqkv_bf : Wout_bf;
        int i = (id < 73728) ? id : (id - 73728);
        const float* sp = src + (size_t)i * 8;
        float4 a = *(const float4*)sp;
        float4 b = *(const float4*)(sp + 4);
        u16 t[8] = {f2bf(a.x), f2bf(a.y), f2bf(a.z), f2bf(a.w),
                    f2bf(b.x), f2bf(b.y), f2bf(b.z), f2bf(b.w)};
        *(uint4*)(dst + (size_t)i * 8) = *(uint4*)t;
    } else if (id < 73728 + 8192 + 4096) {
        int i = id - 73728 - 8192;
        int bi = i >> 6, bj = i & 63;
        size_t e = (size_t)(bi * 64) * SEQ_L + (size_t)bj * 64;
        const unsigned char* p8 = (const unsigned char*)mask;
        unsigned w0 = *(const unsigned*)mask;   // [0][0],[0][1] always true -> format fingerprint
        bool v;
        if (w0 == 0x01010101u || w0 == 0xFFFFFFFFu)      v = p8[e] != 0;
        else if (w0 == 0x3F803F80u || w0 == 0x3C003C00u) v = ((const u16*)mask)[e] != 0;
        else                                             v = ((const unsigned*)mask)[e] != 0;
        cmask[i] = v ? 1 : 0;
    }
}

// ---------------- QKV GEMM, 128x128 tile, async staging + XOR swizzle ----------------
// LDS tiles unpadded (stride 64 u16); 16B chunk c of row r lives at chunk c^(r&7).
__global__ __launch_bounds__(256) void qkv_gemm(
    const u16* __restrict__ X, const u16* __restrict__ W, const float* __restrict__ bias,
    u16* __restrict__ qk, u16* __restrict__ vt) {
    __shared__ __align__(16) u16 As[128 * 64];
    __shared__ __align__(16) u16 Bs[128 * 64];
    int m0 = blockIdx.x * 128, n0 = blockIdx.y * 128;
    int tid = threadIdx.x, lane = tid & 63, w = tid >> 6;
    int ln = lane & 15, quad = lane >> 4;
    int rw = (w >> 1) * 64, cw = (w & 1) * 64;
    int lr8 = lane >> 3, lc = lane & 7;            // staging: 8 rows x 8 chunks per call
    int swz_st = lc ^ (lr8 & 7);                   // source chunk for this lane's LDS slot
    f32x4 acc[4][4] = {};
    for (int kk = 0; kk < 768; kk += 64) {
        __syncthreads();   // WAR: prior MFMA reads done
        #pragma unroll
        for (int j = 0; j < 4; j++) {
            int r0 = w * 32 + j * 8;
            int r = r0 + lr8;
            gload16(X + (size_t)(m0 + r) * 768 + kk + swz_st * 8, As + r0 * 64 + lane * 8);
            gload16(W + (size_t)(n0 + r) * 768 + kk + swz_st * 8, Bs + r0 * 64 + lane * 8);
        }
        __syncthreads();   // drain vmcnt
        #pragma unroll
        for (int s = 0; s < 2; s++) {
            bf16x8 af[4], bfr[4];
            #pragma unroll
            for (int i = 0; i < 4; i++) {
                int R = rw + i * 16 + ln;
                af[i] = *(const bf16x8*)(As + R * 64 + ((4 * s + quad) ^ (ln & 7)) * 8);
            }
            #pragma unroll
            for (int t = 0; t < 4; t++) {
                int R = cw + t * 16 + ln;
                bfr[t] = *(const bf16x8*)(Bs + R * 64 + ((4 * s + quad) ^ (ln & 7)) * 8);
            }
            #pragma unroll
            for (int i = 0; i < 4; i++)
                #pragma unroll
                for (int t = 0; t < 4; t++)
                    acc[i][t] = __builtin_amdgcn_mfma_f32_16x16x32_bf16(af[i], bfr[t], acc[i][t], 0, 0, 0);
        }
    }
    #pragma unroll
    for (int i = 0; i < 4; i++) {
        int row0 = m0 + rw + i * 16 + 4 * quad;   // 4 consecutive rows
        #pragma unroll
        for (int t = 0; t < 4; t++) {
            int col = n0 + cw + t * 16 + ln;
            float bv = bias[col];
            if (col < 512) {
                #pragma unroll
                for (int r = 0; r < 4; r++)
                    qk[(size_t)(row0 + r) * 512 + col] = f2bf(acc[i][t][r] + bv);
            } else {
                int d = col - 512;
                int b = row0 >> 12, seq = row0 & 4095;
                u16 pk[4] = {f2bf(acc[i][t][0] + bv), f2bf(acc[i][t][1] + bv),
                             f2bf(acc[i][t][2] + bv), f2bf(acc[i][t][3] + bv)};
                *(ushort4*)(vt + ((size_t)(b * 2 + (d >> 7)) * 128 + (d & 127)) * SEQ_L + seq)
                    = *(ushort4*)pk;
            }
        }
    }
}

// ---------------- block-sparse flash attention: async double-buffered staging ----------------
__global__ __launch_bounds__(256) void attn_kernel(
    const u16* __restrict__ qk, const u16* __restrict__ vt,
    const unsigned char* __restrict__ cmask, u16* __restrict__ attn_out) {
    __shared__ __align__(16) u16 Ks[2][64 * 128];   // K rows, unpadded + swizzle
    __shared__ __align__(16) u16 Vt[2][128 * 64];   // V^T [d][k], unpadded + swizzle
    __shared__ __align__(16) u16 Ps[4][16 * 72];    // per-wave P staging (VALU-written)

    int idx = blockIdx.x;
    int qi = 63 - (idx >> 3);          // heavy q-blocks first
    int sub = idx & 7, c = sub & 1, b = sub >> 1;
    int tid = threadIdx.x, lane = tid & 63, w = tid >> 6;
    int ln = lane & 15, quad = lane >> 4;
    const float scale = 0.08838834764831845f;  // 1/sqrt(128)

    const u16* kb_base = qk + (size_t)b * SEQ_L * 512 + 256 + c * 128;
    const u16* vt_base = vt + (size_t)(b * 2 + c) * 128 * SEQ_L;

    // staging lane maps
    int k_lr = lane >> 4, k_lc = lane & 15;        // K: 4 rows x 16 chunks / call
    int v_lr = lane >> 3, v_lc = lane & 7;         // V: 8 rows x 8 chunks / call

    // Q fragments: A[m=ln][k=32s+8*quad+j]
    bf16x8 qf[4];
    {
        size_t grow = (size_t)(b * SEQ_L + qi * 64 + w * 16 + ln);
        const u16* qp = qk + grow * 512 + c * 128;
        #pragma unroll
        for (int s = 0; s < 4; s++) qf[s] = *(const bf16x8*)(qp + 32 * s + 8 * quad);
    }
    float m_st[4], l_st[4];
    #pragma unroll
    for (int r = 0; r < 4; r++) { m_st[r] = -1e30f; l_st[r] = 0.f; }
    f32x4 accO[8] = {};

    // active-block bitmap
    const unsigned char* mrow = cmask + qi * 64;
    unsigned long long bm = 0;
    for (int k = 0; k <= qi; k++) bm |= (unsigned long long)(mrow[k] != 0) << k;

    int cur = __ffsll(bm) - 1; bm &= bm - 1;   // diagonal guarantees >=1 active
    int buf = 0;
    // issue loads for first tile
    {
        const u16* kp = kb_base + (size_t)cur * 64 * 512;
        const u16* vp = vt_base + cur * 64;
        #pragma unroll
        for (int j = 0; j < 4; j++) {
            int kr0 = w * 16 + j * 4, kr = kr0 + k_lr;
            gload16(kp + (size_t)kr * 512 + (k_lc ^ (kr & 7)) * 8, Ks[0] + kr0 * 128 + lane * 8);
            int vr0 = w * 32 + j * 8, vr = vr0 + v_lr;
            gload16(vp + (size_t)vr * SEQ_L + (v_lc ^ (vr & 7)) * 8, Vt[0] + vr0 * 64 + lane * 8);
        }
    }
    while (cur >= 0) {
        int nxt = bm ? (__ffsll(bm) - 1) : -1;
        if (bm) bm &= bm - 1;
        __syncthreads();   // drains cur's loads; WAR-protects buf^1 for restage
        if (nxt >= 0) {    // async prefetch next tile into other buffer
            const u16* kp = kb_base + (size_t)nxt * 64 * 512;
            const u16* vp = vt_base + nxt * 64;
            #pragma unroll
            for (int j = 0; j < 4; j++) {
                int kr0 = w * 16 + j * 4, kr = kr0 + k_lr;
                gload16(kp + (size_t)kr * 512 + (k_lc ^ (kr & 7)) * 8, Ks[buf ^ 1] + kr0 * 128 + lane * 8);
                int vr0 = w * 32 + j * 8, vr = vr0 + v_lr;
                gload16(vp + (size_t)vr * SEQ_L + (v_lc ^ (vr & 7)) * 8, Vt[buf ^ 1] + vr0 * 64 + lane * 8);
            }
        }

        // S = Q K^T : D[m=4*quad+r][n=ln+16t]
        f32x4 accS[4] = {};
        #pragma unroll
        for (int s = 0; s < 4; s++) {
            #pragma unroll
            for (int t = 0; t < 4; t++) {
                int R = t * 16 + ln;
                bf16x8 bfr = *(const bf16x8*)(Ks[buf] + R * 128 + ((4 * s + quad) ^ (ln & 7)) * 8);
                accS[t] = __builtin_amdgcn_mfma_f32_16x16x32_bf16(qf[s], bfr, accS[t], 0, 0, 0);
            }
        }

        // online softmax per row m = 4*quad + r
        float P[4][4];
        #pragma unroll
        for (int r = 0; r < 4; r++) {
            float sv[4];
            float mx = -1e30f;
            #pragma unroll
            for (int t = 0; t < 4; t++) { sv[t] = accS[t][r] * scale; mx = fmaxf(mx, sv[t]); }
            #pragma unroll
            for (int off = 1; off < 16; off <<= 1) mx = fmaxf(mx, __shfl_xor(mx, off, 64));
            float nm = fmaxf(m_st[r], mx);
            float alpha = __expf(m_st[r] - nm);
            m_st[r] = nm;
            float rs = 0.f;
            #pragma unroll
            for (int t = 0; t < 4; t++) { float p = __expf(sv[t] - nm); P[t][r] = p; rs += p; }
            #pragma unroll
            for (int off = 1; off < 16; off <<= 1) rs += __shfl_xor(rs, off, 64);
            l_st[r] = l_st[r] * alpha + rs;
            #pragma unroll
            for (int nt = 0; nt < 8; nt++) accO[nt][r] *= alpha;
        }
        // stage P: C/D -> A-operand layout; Ps[w] is wave-private (no barrier needed)
        #pragma unroll
        for (int t = 0; t < 4; t++)
            #pragma unroll
            for (int r = 0; r < 4; r++)
                Ps[w][(4 * quad + r) * 72 + ln + 16 * t] = f2bf(P[t][r]);

        // O += P V
        #pragma unroll
        for (int s2 = 0; s2 < 2; s2++) {
            bf16x8 pf = *(const bf16x8*)(&Ps[w][ln * 72 + 32 * s2 + 8 * quad]);
            #pragma unroll
            for (int nt = 0; nt < 8; nt++) {
                int R = nt * 16 + ln;
                bf16x8 vf = *(const bf16x8*)(Vt[buf] + R * 64 + ((4 * s2 + quad) ^ (ln & 7)) * 8);
                accO[nt] = __builtin_amdgcn_mfma_f32_16x16x32_bf16(pf, vf, accO[nt], 0, 0, 0);
            }
        }
        cur = nxt; buf ^= 1;
    }

    #pragma unroll
    for (int nt = 0; nt < 8; nt++) {
        int col = c * 128 + nt * 16 + ln;
        #pragma unroll
        for (int r = 0; r < 4; r++) {
            int row = b * SEQ_L + qi * 64 + w * 16 + 4 * quad + r;
            float inv = 1.0f / fmaxf(l_st[r], 1e-20f);
            attn_out[(size_t)row * 256 + col] = f2bf(accO[nt][r] * inv);
        }
    }
}

// ---------------- out projection: attn[16384,256](bf16) @ Wout^T + b -> fp32 halves ----------------
__global__ __launch_bounds__(256) void out_gemm(
    const u16* __restrict__ A, const u16* __restrict__ W, const float* __restrict__ bias,
    float* __restrict__ out) {
    __shared__ __align__(16) u16 As[64 * 64];
    __shared__ __align__(16) u16 Bs[64 * 64];
    int m0 = blockIdx.x * 64, n0 = blockIdx.y * 64;
    int tid = threadIdx.x, lane = tid & 63, w = tid >> 6;
    int ln = lane & 15, quad = lane >> 4;
    int lr8 = lane >> 3, lc = lane & 7;
    int swz_st = lc ^ (lr8 & 7);
    f32x4 acc[4] = {};
    for (int kk = 0; kk < 256; kk += 64) {
        __syncthreads();
        #pragma unroll
        for (int j = 0; j < 2; j++) {
            int r0 = w * 16 + j * 8;
            int r = r0 + lr8;
            gload16(A + (size_t)(m0 + r) * 256 + kk + swz_st * 8, As + r0 * 64 + lane * 8);
            gload16(W + (size_t)(n0 + r) * 256 + kk + swz_st * 8, Bs + r0 * 64 + lane * 8);
        }
        __syncthreads();
        #pragma unroll
        for (int s = 0; s < 2; s++) {
            int R = w * 16 + ln;
            bf16x8 af = *(const bf16x8*)(As + R * 64 + ((4 * s + quad) ^ (ln & 7)) * 8);
            #pragma unroll
            for (int t = 0; t < 4; t++) {
                int Rb = t * 16 + ln;
                bf16x8 bfr = *(const bf16x8*)(Bs + Rb * 64 + ((4 * s + quad) ^ (ln & 7)) * 8);
                acc[t] = __builtin_amdgcn_mfma_f32_16x16x32_bf16(af, bfr, acc[t], 0, 0, 0);
            }
        }
    }
    const size_t half = (size_t)M_TOT * 128;
    #pragma unroll
    for (int t = 0; t < 4; t++) {
        int col = n0 + t * 16 + ln;
        float bv = bias[col];
        float* base = (col < 128) ? (out + col) : (out + half + (col - 128));
        #pragma unroll
        for (int r = 0; r < 4; r++) {
            int row = m0 + w * 16 + 4 * quad + r;
            base[(size_t)row * 128] = acc[t][r] + bv;
        }
    }
}

extern "C" void kernel_launch(void* const* d_in, const int* in_sizes, int n_in,
                              void* d_out, int out_size, void* d_ws, size_t ws_size,
                              hipStream_t stream) {
    char* ws = (char*)d_ws;
    u16* x_bf    = (u16*)ws;                          // 16384*768  = 25.2 MB
    u16* qk_buf  = x_bf + (size_t)M_TOT * 768;        // 16384*512  = 16.8 MB
    u16* vt_buf  = qk_buf + (size_t)M_TOT * 512;      // 1024*4096  =  8.4 MB
    u16* attn_bf = vt_buf + (size_t)1024 * SEQ_L;     // 16384*256  =  8.4 MB
    u16* Wqkv_bf = attn_bf + (size_t)M_TOT * 256;     // 589824
    u16* Wout_bf = Wqkv_bf + 589824;                  // 65536
    unsigned char* cmask = (unsigned char*)(Wout_bf + 65536);

    hipLaunchKernelGGL(pack_x, dim3(1024, 6), dim3(256), 0, stream,
                       (const float*)d_in[0], (const float*)d_in[1], (const float*)d_in[2],
                       (const float*)d_in[3], (const float*)d_in[4], (const float*)d_in[5], x_bf);
    hipLaunchKernelGGL(prep, dim3(336), dim3(256), 0, stream,
                       (const float*)d_in[6], (const float*)d_in[8], d_in[10],
                       Wqkv_bf, Wout_bf, cmask);
    hipLaunchKernelGGL(qkv_gemm, dim3(128, 6), dim3(256), 0, stream,
                       x_bf, Wqkv_bf, (const float*)d_in[7], qk_buf, vt_buf);
    hipLaunchKernelGGL(attn_kernel, dim3(512), dim3(256), 0, stream,
                       qk_buf, vt_buf, cmask, attn_bf);
    hipLaunchKernelGGL(out_gemm, dim3(256, 4), dim3(256), 0, stream,
                       attn_bf, Wout_bf, (const float*)d_in[9], (float*)d_out);
}